// Round 2
// baseline (322.482 us; speedup 1.0000x reference)
//
#include <hip/hip_runtime.h>
#include <cstdint>
#include <cstddef>

#define WPITCH 24
#define NCN 8          // node K-chunks (2048/8 = 256)
#define NCE 4          // edge K-chunks (1024/4 = 256)
#define NSUB 8         // 256 floats per chunk = 8 substeps x 32

// ws layout (float offsets)
#define WS_WBIG 0            // 3072*24 = 73728
#define WS_BMAT 73728        // 640*24  = 15360
#define WS_BBIG 89088        // 24
#define WS_ND   89728        // NCN*8192*23 ; edp follows

// output offsets (floats)
#define OUT_IND 0
#define OUT_LAB 28672
#define OUT_LRP 57344
#define OUT_CRP 98304
#define OUT_MRP 122880
#define OUT_LRN 237568
#define OUT_CRN 339968
#define OUT_MRN 401408

__device__ __constant__ int d_pi[28] = {0,0,0,0,0,0,0,1,1,1,1,1,1,2,2,2,2,2,3,3,3,3,4,4,4,5,5,6};
__device__ __constant__ int d_pj[28] = {1,2,3,4,5,6,7,2,3,4,5,6,7,3,4,5,6,7,4,5,6,7,5,6,7,6,7,7};

__device__ __forceinline__ float wh_at(const float* wlr, const float* wcr, const float* wmr,
                                       int j, int h) {
  return (h < 5) ? wlr[j*5 + h] : (h < 8) ? wcr[j*3 + (h-5)] : wmr[j*14 + (h-8)];
}

__device__ __forceinline__ const float* uniform_ptr(const float* p) {
  uint64_t u = (uint64_t)p;
  uint32_t lo = __builtin_amdgcn_readfirstlane((uint32_t)(u & 0xffffffffu));
  uint32_t hi = __builtin_amdgcn_readfirstlane((uint32_t)(u >> 32));
  return (const float*)(((uint64_t)hi << 32) | lo);
}

// ---------------- prep1: Bmat = [T1(128x24); WhE(512x24)] and b_big ----------------
// bid<128: T1 row m (wave-parallel dots from LDS). bid==128: biases. bid>=129: WhE copy.
__global__ __launch_bounds__(256) void prep1(
    const float* __restrict__ w_rel, const float* __restrict__ w_ind2,
    const float* __restrict__ w_lr, const float* __restrict__ w_cr, const float* __restrict__ w_mr,
    const float* __restrict__ b_ind1, const float* __restrict__ b_ind2,
    const float* __restrict__ b_rel,
    const float* __restrict__ b_lr, const float* __restrict__ b_cr, const float* __restrict__ b_mr,
    float* __restrict__ bmat, float* __restrict__ bbig) {
  int bid = blockIdx.x, tid = threadIdx.x;
  if (bid < 128) {                         // T1[m][1+h] = sum_j Wrel2[m][j]*Wh[j][h]
    int m = bid;
    __shared__ float swr[512];
    const float* wr2 = w_rel + (size_t)(3072 + m)*512;
    swr[tid]       = wr2[tid];
    swr[tid + 256] = wr2[tid + 256];
    __syncthreads();
    int h = tid >> 3, q = tid & 7;
    if (h < 22) {
      float a = 0.f;
#pragma unroll 8
      for (int jj = 0; jj < 64; ++jj) {
        int j = jj*8 + q;                  // bank-spread across q
        a = fmaf(swr[j], wh_at(w_lr, w_cr, w_mr, j, h), a);
      }
      a += __shfl_xor(a, 1); a += __shfl_xor(a, 2); a += __shfl_xor(a, 4);
      if (q == 0) bmat[m*24 + 1 + h] = a;
    }
    if (tid == 248) bmat[m*24 + 0]  = w_ind2[m];
    if (tid == 249) bmat[m*24 + 23] = 0.f;
  } else if (bid == 128) {                 // biases
    __shared__ float sbrel[512];
    for (int j = tid; j < 512; j += 256) {
      float a = b_rel[j];
#pragma unroll 4
      for (int m = 0; m < 128; ++m)
        a = fmaf(b_ind1[m], w_rel[(size_t)(3072 + m)*512 + j], a);
      sbrel[j] = a;
    }
    __syncthreads();
    int h = tid >> 3, q = tid & 7;
    if (h < 22) {
      float bh = (h < 5) ? b_lr[h] : (h < 8) ? b_cr[h-5] : b_mr[h-8];
      float a = 0.f;
#pragma unroll 8
      for (int jj = 0; jj < 64; ++jj) {
        int j = jj*8 + q;
        a = fmaf(sbrel[j], wh_at(w_lr, w_cr, w_mr, j, h), a);
      }
      a += __shfl_xor(a, 1); a += __shfl_xor(a, 2); a += __shfl_xor(a, 4);
      if (q == 0) bbig[1 + h] = a + bh;
    } else if (tid >= 248) {               // bbig[0] = b_ind1 . w_ind2 + b_ind2
      int q2 = tid & 7;
      float a = 0.f;
#pragma unroll
      for (int t = 0; t < 16; ++t)
        a = fmaf(b_ind1[q2*16 + t], w_ind2[q2*16 + t], a);
      a += __shfl_xor(a, 1); a += __shfl_xor(a, 2); a += __shfl_xor(a, 4);
      if (tid == 248) bbig[0]  = a + b_ind2[0];
      if (tid == 250) bbig[23] = 0.f;
    }
  } else {                                 // WhE copy: 512*24 slots, bids 129..176
    int idx = (bid - 129)*256 + tid;
    int j = idx / 24, n = idx % 24;
    float v = (n >= 1 && n <= 22) ? wh_at(w_lr, w_cr, w_mr, j, n - 1) : 0.f;
    bmat[(128 + j)*24 + n] = v;
  }
}

// ---------------- prep2: W_big[k][n] = [W_ind1|W_rel][k] . Bmat[:,n], 2 lanes per output
__global__ __launch_bounds__(256) void prep2(
    const float* __restrict__ w_ind1, const float* __restrict__ w_rel,
    const float* __restrict__ bmat, float* __restrict__ wbig) {
  int g = blockIdx.x*256 + threadIdx.x;    // 147456 = 73728 outputs x 2 halves
  int gid = g >> 1, half = g & 1;
  int k = gid / 24, n = gid % 24;
  float a = 0.f;
  if (n != 23) {
    const float* wr = w_rel + (size_t)k*512;
    if (half == 0) {
      const float* w1 = w_ind1 + (size_t)k*128;
#pragma unroll 8
      for (int i = 0; i < 128; ++i) a = fmaf(w1[i], bmat[i*24 + n], a);
#pragma unroll 8
      for (int j = 0; j < 192; ++j) a = fmaf(wr[j], bmat[(128 + j)*24 + n], a);
    } else {
#pragma unroll 8
      for (int j = 192; j < 512; ++j) a = fmaf(wr[j], bmat[(128 + j)*24 + n], a);
    }
  }
  a += __shfl_xor(a, 1);
  if (half == 0) wbig[gid] = a;
}

// ---------------- kmain: partial dot-products; lane=row; scalar W; pipelined loads
__global__ __launch_bounds__(256, 3) void kmain(
    const float* __restrict__ nf, const float* __restrict__ intf,
    const float* __restrict__ wbig, float* __restrict__ ndp, float* __restrict__ edp) {
  __shared__ float4 tile[4][512];          // 8 KB per wave, no cross-wave sharing
  int tid = threadIdx.x;
  int l = tid & 63;
  int w = tid >> 6;
  int bid = blockIdx.x;
  bool isNode = bid < 32*NCN;

  int R0, kLoc, wOff;
  float* outp;
  if (isNode) {
    int chunk = bid % NCN, rg = bid / NCN;
    kLoc = chunk*256; wOff = kLoc;
    outp = ndp + (size_t)chunk*8192*23;
    R0 = rg*256 + w*64;
  } else {
    int eb = bid - 32*NCN;
    int chunk = eb % NCE, rg = eb / NCE;
    kLoc = chunk*256; wOff = 2048 + kLoc;
    outp = edp + (size_t)chunk*28672*23;
    R0 = rg*256 + w*64;
  }
  const float* wbu = uniform_ptr(wbig + (size_t)wOff*WPITCH);  // SGPR base -> s_load

  int lg = l >> 3, f0 = l & 7, fs = f0 ^ lg;
  const float4* bases[8];
#pragma unroll
  for (int q = 0; q < 8; ++q) {
    int row = R0 + q*8 + lg;
    const float* rp;
    if (isNode) rp = nf + (size_t)row*2048;
    else {
      int b = row / 28, p = row % 28;
      rp = intf + (size_t)(b*64 + d_pi[p]*8 + d_pj[p])*1024;
    }
    bases[q] = (const float4*)(rp + kLoc);
  }

  float acc[23];
#pragma unroll
  for (int n = 0; n < 23; ++n) acc[n] = 0.f;
  float4* tw = &tile[w][0];

  float4 v[8], vn[8];
#pragma unroll
  for (int q = 0; q < 8; ++q) v[q] = bases[q][f0];   // prologue: substep 0

#pragma unroll 1
  for (int ss = 0; ss < NSUB; ++ss) {
    // stage current substep to LDS (XOR-swizzled; compiler inserts vmcnt wait)
#pragma unroll
    for (int q = 0; q < 8; ++q) tw[(q*8 + lg)*8 + fs] = v[q];
    // prefetch next substep while we compute (HBM latency hides under FMAs)
    if (ss + 1 < NSUB) {
#pragma unroll
      for (int q = 0; q < 8; ++q) vn[q] = bases[q][(ss + 1)*8 + f0];
    }
    const float* wr0 = wbu + ss*32*WPITCH;
#pragma unroll
    for (int k4 = 0; k4 < 8; ++k4) {
      float4 x = tw[l*8 + (k4 ^ f0)];
#pragma unroll
      for (int s = 0; s < 4; ++s) {
        float xs = (s == 0) ? x.x : (s == 1) ? x.y : (s == 2) ? x.z : x.w;
        const float* wr = wr0 + (k4*4 + s)*WPITCH;
#pragma unroll
        for (int n = 0; n < 23; ++n)
          acc[n] = fmaf(xs, wr[n], acc[n]);
      }
    }
#pragma unroll
    for (int q = 0; q < 8; ++q) v[q] = vn[q];
  }

  // transpose through this wave's LDS region, then coalesced partial store
  float* t = (float*)tw;
#pragma unroll
  for (int n = 0; n < 23; ++n) t[l*24 + n] = acc[n];
  float* op = outp + (size_t)R0*23;
  for (int g = l; g < 64*23; g += 64)
    op[g] = t[(g/23)*24 + (g%23)];
}

// ---------------- kcombine: one batch per block; sum partials, bias, sigmoid, scatter
__global__ __launch_bounds__(256) void kcombine(
    const float* __restrict__ ndp, const float* __restrict__ edp,
    const float* __restrict__ bbig, const int* __restrict__ opairs,
    float* __restrict__ out) {
  __shared__ float snd[184];
  __shared__ int spos[8];
  int b = blockIdx.x, tid = threadIdx.x;
  if (tid < 184) {
    int o = tid / 23, n = tid % 23;
    float s = 0.f;
#pragma unroll
    for (int c = 0; c < NCN; ++c)
      s += ndp[((size_t)c*8192 + b*8 + o)*23 + n];
    snd[tid] = s;
  } else if (tid < 192) {
    int r = tid - 184;
    int oi = opairs[b*16 + r*2], oj = opairs[b*16 + r*2 + 1];
    int a = min(oi, oj), bb = max(oi, oj);
    spos[r] = 7*a - (a*(a+1))/2 + bb - 1;
  }
  __syncthreads();
  for (int g = tid; g < 644; g += 256) {
    int p = g / 23, n = g % 23;
    float ed = 0.f;
#pragma unroll
    for (int c = 0; c < NCE; ++c)
      ed += edp[((size_t)c*28672 + b*28 + p)*23 + n];
    float val = 0.5f*(snd[d_pi[p]*23 + n] + snd[d_pj[p]*23 + n]) + ed + bbig[n];
    int slot = -1, below = 0;
#pragma unroll
    for (int r = 0; r < 8; ++r) {
      int pl = spos[r];
      slot = (pl == p) ? r : slot;
      below += (pl < p) ? 1 : 0;
    }
    if (n == 0) {
      out[OUT_IND + b*28 + p] = 1.f/(1.f + expf(-val));
      out[OUT_LAB + b*28 + p] = (slot >= 0) ? 1.f : 0.f;
    } else {
      int h = n - 1;
      if (slot >= 0) {
        int rr = b*8 + slot;
        if (h < 5)      out[OUT_LRP + rr*5  + h]     = val;
        else if (h < 8) out[OUT_CRP + rr*3  + (h-5)] = val;
        else            out[OUT_MRP + rr*14 + (h-8)] = val;
      } else {
        int s = p - below;
        int rr = b*20 + s;
        if (h < 5)      out[OUT_LRN + rr*5  + h]     = val;
        else if (h < 8) out[OUT_CRN + rr*3  + (h-5)] = val;
        else            out[OUT_MRN + rr*14 + (h-8)] = val;
      }
    }
  }
}

extern "C" void kernel_launch(void* const* d_in, const int* in_sizes, int n_in,
                              void* d_out, int out_size, void* d_ws, size_t ws_size,
                              hipStream_t stream) {
  const float* nf     = (const float*)d_in[0];
  const float* intf   = (const float*)d_in[1];
  const int*   opairs = (const int*)d_in[2];
  const float* w_ind1 = (const float*)d_in[3];
  const float* b_ind1 = (const float*)d_in[4];
  const float* w_ind2 = (const float*)d_in[5];
  const float* b_ind2 = (const float*)d_in[6];
  const float* w_rel  = (const float*)d_in[7];
  const float* b_rel  = (const float*)d_in[8];
  const float* w_cr   = (const float*)d_in[9];
  const float* b_cr   = (const float*)d_in[10];
  const float* w_lr   = (const float*)d_in[11];
  const float* b_lr   = (const float*)d_in[12];
  const float* w_mr   = (const float*)d_in[13];
  const float* b_mr   = (const float*)d_in[14];
  float* out = (float*)d_out;
  float* ws  = (float*)d_ws;

  float* wbig = ws + WS_WBIG;
  float* bmat = ws + WS_BMAT;
  float* bbig = ws + WS_BBIG;
  float* ndp  = ws + WS_ND;
  float* edp  = ndp + (size_t)NCN*8192*23;

  prep1<<<177, 256, 0, stream>>>(w_rel, w_ind2, w_lr, w_cr, w_mr,
                                 b_ind1, b_ind2, b_rel, b_lr, b_cr, b_mr, bmat, bbig);
  prep2<<<576, 256, 0, stream>>>(w_ind1, w_rel, bmat, wbig);
  kmain<<<32*NCN + 112*NCE, 256, 0, stream>>>(nf, intf, wbig, ndp, edp);
  kcombine<<<1024, 256, 0, stream>>>(ndp, edp, bbig, opairs, out);
}

// Round 3
// 209.201 us; speedup vs baseline: 1.5415x; 1.5415x over previous
//
#include <hip/hip_runtime.h>
#include <cstdint>
#include <cstddef>

#define WPITCH 24
#define NCN 8          // node K-chunks (2048/8 = 256)
#define NCE 4          // edge K-chunks (1024/4 = 256)

// ws layout (float offsets)
#define WS_WBIG 0            // 3072*24 = 73728
#define WS_BMAT 73728        // 640*24  = 15360
#define WS_BBIG 89088        // 24
#define WS_ND   89728        // NCN*8192*23 ; edp follows

// output offsets (floats)
#define OUT_IND 0
#define OUT_LAB 28672
#define OUT_LRP 57344
#define OUT_CRP 98304
#define OUT_MRP 122880
#define OUT_LRN 237568
#define OUT_CRN 339968
#define OUT_MRN 401408

__device__ __constant__ int d_pi[28] = {0,0,0,0,0,0,0,1,1,1,1,1,1,2,2,2,2,2,3,3,3,3,4,4,4,5,5,6};
__device__ __constant__ int d_pj[28] = {1,2,3,4,5,6,7,2,3,4,5,6,7,3,4,5,6,7,4,5,6,7,5,6,7,6,7,7};

__device__ __forceinline__ float wh_at(const float* wlr, const float* wcr, const float* wmr,
                                       int j, int h) {
  return (h < 5) ? wlr[j*5 + h] : (h < 8) ? wcr[j*3 + (h-5)] : wmr[j*14 + (h-8)];
}

__device__ __forceinline__ const float* uniform_ptr(const float* p) {
  uint64_t u = (uint64_t)p;
  uint32_t lo = __builtin_amdgcn_readfirstlane((uint32_t)(u & 0xffffffffu));
  uint32_t hi = __builtin_amdgcn_readfirstlane((uint32_t)(u >> 32));
  return (const float*)(((uint64_t)hi << 32) | lo);
}

// global -> LDS direct (16B per lane); LDS dest = uniform base + lane*16
__device__ __forceinline__ void load_lds16(const float* g, float* l) {
  __builtin_amdgcn_global_load_lds((const __attribute__((address_space(1))) void*)g,
                                   (__attribute__((address_space(3))) void*)l, 16, 0, 0);
}

// ---------------- prep1: Bmat = [T1(128x24); WhE(512x24)] and b_big ----------------
__global__ __launch_bounds__(256) void prep1(
    const float* __restrict__ w_rel, const float* __restrict__ w_ind2,
    const float* __restrict__ w_lr, const float* __restrict__ w_cr, const float* __restrict__ w_mr,
    const float* __restrict__ b_ind1, const float* __restrict__ b_ind2,
    const float* __restrict__ b_rel,
    const float* __restrict__ b_lr, const float* __restrict__ b_cr, const float* __restrict__ b_mr,
    float* __restrict__ bmat, float* __restrict__ bbig) {
  int bid = blockIdx.x, tid = threadIdx.x;
  if (bid < 128) {                         // T1[m][1+h] = sum_j Wrel2[m][j]*Wh[j][h]
    int m = bid;
    __shared__ float swr[512];
    const float* wr2 = w_rel + (size_t)(3072 + m)*512;
    swr[tid]       = wr2[tid];
    swr[tid + 256] = wr2[tid + 256];
    __syncthreads();
    int h = tid >> 3, q = tid & 7;
    if (h < 22) {
      float a = 0.f;
#pragma unroll 8
      for (int jj = 0; jj < 64; ++jj) {
        int j = jj*8 + q;
        a = fmaf(swr[j], wh_at(w_lr, w_cr, w_mr, j, h), a);
      }
      a += __shfl_xor(a, 1); a += __shfl_xor(a, 2); a += __shfl_xor(a, 4);
      if (q == 0) bmat[m*24 + 1 + h] = a;
    }
    if (tid == 248) bmat[m*24 + 0]  = w_ind2[m];
    if (tid == 249) bmat[m*24 + 23] = 0.f;
  } else if (bid == 128) {                 // biases
    __shared__ float sbrel[512];
    for (int j = tid; j < 512; j += 256) {
      float a = b_rel[j];
#pragma unroll 4
      for (int m = 0; m < 128; ++m)
        a = fmaf(b_ind1[m], w_rel[(size_t)(3072 + m)*512 + j], a);
      sbrel[j] = a;
    }
    __syncthreads();
    int h = tid >> 3, q = tid & 7;
    if (h < 22) {
      float bh = (h < 5) ? b_lr[h] : (h < 8) ? b_cr[h-5] : b_mr[h-8];
      float a = 0.f;
#pragma unroll 8
      for (int jj = 0; jj < 64; ++jj) {
        int j = jj*8 + q;
        a = fmaf(sbrel[j], wh_at(w_lr, w_cr, w_mr, j, h), a);
      }
      a += __shfl_xor(a, 1); a += __shfl_xor(a, 2); a += __shfl_xor(a, 4);
      if (q == 0) bbig[1 + h] = a + bh;
    } else if (tid >= 248) {
      int q2 = tid & 7;
      float a = 0.f;
#pragma unroll
      for (int t = 0; t < 16; ++t)
        a = fmaf(b_ind1[q2*16 + t], w_ind2[q2*16 + t], a);
      a += __shfl_xor(a, 1); a += __shfl_xor(a, 2); a += __shfl_xor(a, 4);
      if (tid == 248) bbig[0]  = a + b_ind2[0];
      if (tid == 250) bbig[23] = 0.f;
    }
  } else {                                 // WhE copy: bids 129..176
    int idx = (bid - 129)*256 + tid;
    int j = idx / 24, n = idx % 24;
    float v = (n >= 1 && n <= 22) ? wh_at(w_lr, w_cr, w_mr, j, n - 1) : 0.f;
    bmat[(128 + j)*24 + n] = v;
  }
}

// ---------------- prep2: W_big[k][n] = [W_ind1|W_rel][k] . Bmat[:,n]
__global__ __launch_bounds__(256) void prep2(
    const float* __restrict__ w_ind1, const float* __restrict__ w_rel,
    const float* __restrict__ bmat, float* __restrict__ wbig) {
  int g = blockIdx.x*256 + threadIdx.x;    // 147456 = 73728 outputs x 2 halves
  int gid = g >> 1, half = g & 1;
  int k = gid / 24, n = gid % 24;
  float a = 0.f;
  if (n != 23) {
    const float* wr = w_rel + (size_t)k*512;
    if (half == 0) {
      const float* w1 = w_ind1 + (size_t)k*128;
#pragma unroll 8
      for (int i = 0; i < 128; ++i) a = fmaf(w1[i], bmat[i*24 + n], a);
#pragma unroll 8
      for (int j = 0; j < 192; ++j) a = fmaf(wr[j], bmat[(128 + j)*24 + n], a);
    } else {
#pragma unroll 8
      for (int j = 192; j < 512; ++j) a = fmaf(wr[j], bmat[(128 + j)*24 + n], a);
    }
  }
  a += __shfl_xor(a, 1);
  if (half == 0) wbig[gid] = a;
}

// ---------------- kmain: X staged via global_load_lds; W scalar; lane = row ----------------
// Per wave: 64 rows x 256 k. 16 substeps of 16 floats/row.
// LDS tile per wave: [64 rows][4 float4 slots], slot XOR-swizzled by (row&3)^((row>>2)&3).
__global__ __launch_bounds__(256) void kmain(
    const float* __restrict__ nf, const float* __restrict__ intf,
    const float* __restrict__ wbig, float* __restrict__ ndp, float* __restrict__ edp) {
  __shared__ float tile[4][1536];          // per wave: 1024 stage + overflow for epilogue transpose
  const int tid = threadIdx.x;
  const int l = tid & 63;
  const int w = tid >> 6;
  const int bid = blockIdx.x;
  const bool isNode = bid < 32*NCN;

  int R0, kLoc, wOff;
  float* outp;
  if (isNode) {
    int chunk = bid % NCN, rg = bid / NCN;
    kLoc = chunk*256; wOff = kLoc;
    outp = ndp + (size_t)chunk*8192*23;
    R0 = rg*256 + w*64;
  } else {
    int eb = bid - 32*NCN;
    int chunk = eb % NCE, rg = eb / NCE;
    kLoc = chunk*256; wOff = 2048 + kLoc;
    outp = edp + (size_t)chunk*28672*23;
    R0 = rg*256 + w*64;
  }
  const float* wbu = uniform_ptr(wbig + (size_t)wOff*WPITCH);  // SGPR base -> s_load

  // staging sources: instr q covers tile rows [q*16, q*16+16); lane l -> row q*16+(l>>2), slot l&3
  const float* src[4];
  {
    int srow = l >> 2, slot = l & 3;
#pragma unroll
    for (int q = 0; q < 4; ++q) {
      int tr = q*16 + srow;
      int grow = R0 + tr;
      const float* rp;
      if (isNode) rp = nf + (size_t)grow*2048;
      else {
        int b = grow / 28, p = grow % 28;
        rp = intf + (size_t)(b*64 + d_pi[p]*8 + d_pj[p])*1024;
      }
      int sw = (tr & 3) ^ ((tr >> 2) & 3);
      src[q] = rp + kLoc + ((slot ^ sw) << 2);   // pre-swizzled source, linear LDS dest
    }
  }
  float* buf = &tile[w][0];
  const int sl = (l & 3) ^ ((l >> 2) & 3);       // read-side swizzle for this lane's row (=l)

  float acc[23];
#pragma unroll
  for (int n = 0; n < 23; ++n) acc[n] = 0.f;

#pragma unroll 1
  for (int ss = 0; ss < 16; ++ss) {
    // stage this substep: 4 x 1KB direct-to-LDS (no VGPR round trip)
#pragma unroll
    for (int q = 0; q < 4; ++q)
      load_lds16(src[q] + ss*16, buf + q*256);
    asm volatile("s_waitcnt vmcnt(0)" ::: "memory");
    __builtin_amdgcn_sched_barrier(0);

    const float* wr0 = wbu + ss*16*WPITCH;
#pragma unroll
    for (int k4 = 0; k4 < 4; ++k4) {
      float4 x = *(const float4*)(buf + l*16 + ((k4 ^ sl) << 2));
      const float* wr = wr0 + k4*4*WPITCH;
#pragma unroll
      for (int e = 0; e < 4; ++e) {
        float xs = (e == 0) ? x.x : (e == 1) ? x.y : (e == 2) ? x.z : x.w;
        const float* wrr = wr + e*WPITCH;
#pragma unroll
        for (int n = 0; n < 23; ++n)
          acc[n] = fmaf(xs, wrr[n], acc[n]);
      }
    }
    asm volatile("" ::: "memory");   // keep ds_reads of this substep before next overwrite
    __builtin_amdgcn_sched_barrier(0);
  }

  // epilogue: transpose through this wave's LDS region (1536 floats), coalesced store
  float* t = buf;
#pragma unroll
  for (int n = 0; n < 23; ++n) t[l*24 + n] = acc[n];
  asm volatile("s_waitcnt lgkmcnt(0)" ::: "memory");
  __builtin_amdgcn_sched_barrier(0);
  float* op = outp + (size_t)R0*23;
#pragma unroll
  for (int i = 0; i < 23; ++i) {
    int g = i*64 + l;
    op[g] = t[(g/23)*24 + (g%23)];
  }
}

// ---------------- kcombine: one batch per block ----------------
__global__ __launch_bounds__(256) void kcombine(
    const float* __restrict__ ndp, const float* __restrict__ edp,
    const float* __restrict__ bbig, const int* __restrict__ opairs,
    float* __restrict__ out) {
  __shared__ float snd[184];
  __shared__ int spos[8];
  int b = blockIdx.x, tid = threadIdx.x;
  if (tid < 184) {
    int o = tid / 23, n = tid % 23;
    float s = 0.f;
#pragma unroll
    for (int c = 0; c < NCN; ++c)
      s += ndp[((size_t)c*8192 + b*8 + o)*23 + n];
    snd[tid] = s;
  } else if (tid < 192) {
    int r = tid - 184;
    int oi = opairs[b*16 + r*2], oj = opairs[b*16 + r*2 + 1];
    int a = min(oi, oj), bb = max(oi, oj);
    spos[r] = 7*a - (a*(a+1))/2 + bb - 1;
  }
  __syncthreads();
  for (int g = tid; g < 644; g += 256) {
    int p = g / 23, n = g % 23;
    float ed = 0.f;
#pragma unroll
    for (int c = 0; c < NCE; ++c)
      ed += edp[((size_t)c*28672 + b*28 + p)*23 + n];
    float val = 0.5f*(snd[d_pi[p]*23 + n] + snd[d_pj[p]*23 + n]) + ed + bbig[n];
    int slot = -1, below = 0;
#pragma unroll
    for (int r = 0; r < 8; ++r) {
      int pl = spos[r];
      slot = (pl == p) ? r : slot;
      below += (pl < p) ? 1 : 0;
    }
    if (n == 0) {
      out[OUT_IND + b*28 + p] = 1.f/(1.f + expf(-val));
      out[OUT_LAB + b*28 + p] = (slot >= 0) ? 1.f : 0.f;
    } else {
      int h = n - 1;
      if (slot >= 0) {
        int rr = b*8 + slot;
        if (h < 5)      out[OUT_LRP + rr*5  + h]     = val;
        else if (h < 8) out[OUT_CRP + rr*3  + (h-5)] = val;
        else            out[OUT_MRP + rr*14 + (h-8)] = val;
      } else {
        int s = p - below;
        int rr = b*20 + s;
        if (h < 5)      out[OUT_LRN + rr*5  + h]     = val;
        else if (h < 8) out[OUT_CRN + rr*3  + (h-5)] = val;
        else            out[OUT_MRN + rr*14 + (h-8)] = val;
      }
    }
  }
}

extern "C" void kernel_launch(void* const* d_in, const int* in_sizes, int n_in,
                              void* d_out, int out_size, void* d_ws, size_t ws_size,
                              hipStream_t stream) {
  const float* nf     = (const float*)d_in[0];
  const float* intf   = (const float*)d_in[1];
  const int*   opairs = (const int*)d_in[2];
  const float* w_ind1 = (const float*)d_in[3];
  const float* b_ind1 = (const float*)d_in[4];
  const float* w_ind2 = (const float*)d_in[5];
  const float* b_ind2 = (const float*)d_in[6];
  const float* w_rel  = (const float*)d_in[7];
  const float* b_rel  = (const float*)d_in[8];
  const float* w_cr   = (const float*)d_in[9];
  const float* b_cr   = (const float*)d_in[10];
  const float* w_lr   = (const float*)d_in[11];
  const float* b_lr   = (const float*)d_in[12];
  const float* w_mr   = (const float*)d_in[13];
  const float* b_mr   = (const float*)d_in[14];
  float* out = (float*)d_out;
  float* ws  = (float*)d_ws;

  float* wbig = ws + WS_WBIG;
  float* bmat = ws + WS_BMAT;
  float* bbig = ws + WS_BBIG;
  float* ndp  = ws + WS_ND;
  float* edp  = ndp + (size_t)NCN*8192*23;

  prep1<<<177, 256, 0, stream>>>(w_rel, w_ind2, w_lr, w_cr, w_mr,
                                 b_ind1, b_ind2, b_rel, b_lr, b_cr, b_mr, bmat, bbig);
  prep2<<<576, 256, 0, stream>>>(w_ind1, w_rel, bmat, wbig);
  kmain<<<32*NCN + 112*NCE, 256, 0, stream>>>(nf, intf, wbig, ndp, edp);
  kcombine<<<1024, 256, 0, stream>>>(ndp, edp, bbig, opairs, out);
}